// Round 2
// baseline (9358.200 us; speedup 1.0000x reference)
//
#include <hip/hip_runtime.h>

// DiffusionConvolution: out[b,n,o] = bias[o] + sum_{s,k,d} (A_s^k x0)[n,(d,b)] * W[(3s+k)*64+d, o]
// B=32, N=20000, D=OUT=64, K=2, E=640000 per support.
//
// R2: bf16 gather pipeline. x0 repacked once to bf16 [n][b*64+d] (82 MB);
// X1 intermediate stored bf16; W tile held in LDS as bf16 (LDS 16.9 KB -> 8 blocks/CU).
// k=0 term stays full fp32 (dominant magnitude). fp32 accumulation throughout.
// Edges interleaved int2{col, val_bits}; gather loop unrolled x2 for MLP.

constexpr int B = 32;
constexpr int D = 64;
constexpr int C = B * D;   // 2048 features per node

__device__ __forceinline__ void fma4(float4& a, float s, const float4 b) {
  a.x = fmaf(s, b.x, a.x);
  a.y = fmaf(s, b.y, a.y);
  a.z = fmaf(s, b.z, a.z);
  a.w = fmaf(s, b.w, a.w);
}

__device__ __forceinline__ unsigned f2bf(float f) {
  union { float f; unsigned u; } v; v.f = f;
  return (v.u + 0x7fffu + ((v.u >> 16) & 1u)) >> 16;   // RNE
}
__device__ __forceinline__ unsigned pk(float a, float b) {
  return f2bf(a) | (f2bf(b) << 16);
}
__device__ __forceinline__ float bflo(unsigned u) { return __uint_as_float(u << 16); }
__device__ __forceinline__ float bfhi(unsigned u) { return __uint_as_float(u & 0xffff0000u); }

__device__ __forceinline__ void fma8(float4& a0, float4& a1, float v, uint4 u) {
  a0.x = fmaf(v, bflo(u.x), a0.x); a0.y = fmaf(v, bfhi(u.x), a0.y);
  a0.z = fmaf(v, bflo(u.y), a0.z); a0.w = fmaf(v, bfhi(u.y), a0.w);
  a1.x = fmaf(v, bflo(u.z), a1.x); a1.y = fmaf(v, bfhi(u.z), a1.y);
  a1.z = fmaf(v, bflo(u.w), a1.z); a1.w = fmaf(v, bfhi(u.w), a1.w);
}

// ---------------- pack x0 -> bf16 [n][b*64+d] ----------------

__global__ __launch_bounds__(256) void pack_x0(const float4* __restrict__ inp4,
                                               ushort4* __restrict__ x0b4, int N) {
  int g = blockIdx.x * 256 + threadIdx.x;            // over N*512 float4s
  if (g >= N * 512) return;
  int n = g >> 9;
  int j = g & 511;                                   // float4 index in row: b=j>>4, d4=j&15
  int b = j >> 4, d4 = j & 15;
  float4 v = inp4[((size_t)b * N + n) * 16 + d4];
  ushort4 o;
  o.x = (ushort)f2bf(v.x); o.y = (ushort)f2bf(v.y);
  o.z = (ushort)f2bf(v.z); o.w = (ushort)f2bf(v.w);
  x0b4[g] = o;
}

// ---------------- CSR build ----------------

__global__ __launch_bounds__(256) void hist_k(const int* __restrict__ rows,
                                              int* __restrict__ counts, int E) {
  int e = blockIdx.x * 256 + threadIdx.x;
  if (e < E) atomicAdd(&counts[rows[e]], 1);
}

__global__ __launch_bounds__(256) void scan_k(const int* __restrict__ counts,
                                              int* __restrict__ row_ptr, int N) {
  __shared__ int part[256];
  int t = threadIdx.x;
  int chunk = (N + 255) >> 8;
  int lo = t * chunk; if (lo > N) lo = N;
  int hi = lo + chunk; if (hi > N) hi = N;
  int s = 0;
  for (int i = lo; i < hi; ++i) s += counts[i];
  part[t] = s;
  __syncthreads();
  for (int off = 1; off < 256; off <<= 1) {
    int x = (t >= off) ? part[t - off] : 0;
    __syncthreads();
    part[t] += x;
    __syncthreads();
  }
  int run = part[t] - s;
  for (int i = lo; i < hi; ++i) { row_ptr[i] = run; run += counts[i]; }
  if (t == 255) row_ptr[N] = part[255];
}

__global__ __launch_bounds__(256) void fill_k(const int* __restrict__ rows,
                                              const int* __restrict__ cols,
                                              const float* __restrict__ vals,
                                              const int* __restrict__ row_ptr,
                                              int* __restrict__ cursor,
                                              int2* __restrict__ edges, int E) {
  int e = blockIdx.x * 256 + threadIdx.x;
  if (e < E) {
    int r = rows[e];
    int pos = row_ptr[r] + atomicAdd(&cursor[r], 1);
    int2 ed;
    ed.x = cols[e];
    ed.y = __float_as_int(vals[e]);
    edges[pos] = ed;
  }
}

// ---------------- k=0 GEMM (fp32): out = bias + x0 * (W[0:64] + W[192:256]) ----------------

__global__ __launch_bounds__(256) void k0_gemm(const float4* __restrict__ inp4,
                                               const float4* __restrict__ W4,
                                               const float4* __restrict__ bias4,
                                               float4* __restrict__ out4, int N) {
  __shared__ float sA[64 * 65];
  __shared__ float4 sW[64 * 16];
  int t = threadIdx.x;
  int b = blockIdx.y;
  int n0 = blockIdx.x * 64;

#pragma unroll
  for (int k = 0; k < 4; ++k) {
    int l = t + 256 * k;
    float4 w0 = W4[l];
    float4 w1 = W4[192 * 16 + l];
    w0.x += w1.x; w0.y += w1.y; w0.z += w1.z; w0.w += w1.w;
    sW[l] = w0;
  }
#pragma unroll
  for (int k = 0; k < 4; ++k) {
    int q = t + 256 * k;
    int r = q >> 4, d4 = q & 15;
    int n = n0 + r;
    float4 v = {0.f, 0.f, 0.f, 0.f};
    if (n < N) v = inp4[((size_t)b * N + n) * 16 + d4];
    float* sp = &sA[r * 65 + d4 * 4];
    sp[0] = v.x; sp[1] = v.y; sp[2] = v.z; sp[3] = v.w;
  }
  __syncthreads();

  int np = t >> 3;
  int og = t & 7;
  float4 bz0 = bias4[og * 2], bz1 = bias4[og * 2 + 1];
  float4 a00 = bz0, a01 = bz1, a10 = bz0, a11 = bz1;
  const float* ap0 = &sA[(np * 2) * 65];
  const float* ap1 = ap0 + 65;
#pragma unroll
  for (int d = 0; d < 64; ++d) {
    float x0 = ap0[d], x1 = ap1[d];
    float4 w0 = sW[d * 16 + og * 2];
    float4 w1 = sW[d * 16 + og * 2 + 1];
    fma4(a00, x0, w0); fma4(a01, x0, w1);
    fma4(a10, x1, w0); fma4(a11, x1, w1);
  }
  int n = n0 + np * 2;
  if (n < N) {
    out4[((size_t)b * N + n) * 16 + og * 2] = a00;
    out4[((size_t)b * N + n) * 16 + og * 2 + 1] = a01;
  }
  if (n + 1 < N) {
    out4[((size_t)b * N + n + 1) * 16 + og * 2] = a10;
    out4[((size_t)b * N + n + 1) * 16 + og * 2 + 1] = a11;
  }
}

// ---------------- SpMM (bf16 gather) + fused projection ----------------
// One block per row n. Thread t owns features 8t..8t+7 (b=t>>3, d0=(t&7)*8).
// Gather: one uint4 (8 bf16) per edge per thread, fp32 accumulate.
// Epilogue: 32b x 64d through bf16 W tile (LDS) -> out[b,n,og*8..+7] RMW.

template <bool WRITE_X>
__global__ __launch_bounds__(256, 8) void spmm_proj(const uint4* __restrict__ src,
                                                    const int* __restrict__ row_ptr,
                                                    const int2* __restrict__ edges,
                                                    const float4* __restrict__ Wslice4,
                                                    uint4* __restrict__ Xout,
                                                    float4* __restrict__ out4, int N) {
  __shared__ unsigned sW[2048];   // 8 KB: bf16 W[d][o], uint = o-pair
  __shared__ float sAcc[32 * 68]; // 8.7 KB: [b][d], stride 68 (16B-aligned, conflict-free)
  int t = threadIdx.x;
  int n = blockIdx.x;

#pragma unroll
  for (int k = 0; k < 4; ++k) {
    int l = t + 256 * k;                    // d = l>>4, o4 = l&15
    float4 w = Wslice4[l];
    ((uint2*)sW)[l] = make_uint2(pk(w.x, w.y), pk(w.z, w.w));
  }

  float4 acc0 = {0.f, 0.f, 0.f, 0.f};
  float4 acc1 = {0.f, 0.f, 0.f, 0.f};
  int start = row_ptr[n], end = row_ptr[n + 1];
  const uint4* sp = src + t;

  int e = start;
  for (; e + 2 <= end; e += 2) {
    int2 e0 = edges[e];
    int2 e1 = edges[e + 1];
    uint4 u0 = sp[(size_t)e0.x * 256];
    uint4 u1 = sp[(size_t)e1.x * 256];
    fma8(acc0, acc1, __int_as_float(e0.y), u0);
    fma8(acc0, acc1, __int_as_float(e1.y), u1);
  }
  if (e < end) {
    int2 e0 = edges[e];
    uint4 u0 = sp[(size_t)e0.x * 256];
    fma8(acc0, acc1, __int_as_float(e0.y), u0);
  }

  if (WRITE_X) {
    Xout[(size_t)n * 256 + t] = make_uint4(pk(acc0.x, acc0.y), pk(acc0.z, acc0.w),
                                           pk(acc1.x, acc1.y), pk(acc1.z, acc1.w));
  }

  {  // stash: b = t>>3, d0 = (t&7)*8
    float4* s = (float4*)&sAcc[(t >> 3) * 68 + (t & 7) * 8];
    s[0] = acc0;
    s[1] = acc1;
  }
  __syncthreads();

  // mini-GEMM: thread -> (b = t>>3, outs og*8..og*8+7)
  int bb = t >> 3;
  int og = t & 7;
  float4 o0 = {0.f, 0.f, 0.f, 0.f};
  float4 o1 = {0.f, 0.f, 0.f, 0.f};
  const float* ap = &sAcc[bb * 68];
  const uint4* sW4 = (const uint4*)sW;
#pragma unroll
  for (int d = 0; d < 64; ++d) {
    float a = ap[d];
    uint4 w = sW4[d * 8 + og];
    o0.x = fmaf(a, bflo(w.x), o0.x); o0.y = fmaf(a, bfhi(w.x), o0.y);
    o0.z = fmaf(a, bflo(w.y), o0.z); o0.w = fmaf(a, bfhi(w.y), o0.w);
    o1.x = fmaf(a, bflo(w.z), o1.x); o1.y = fmaf(a, bfhi(w.z), o1.y);
    o1.z = fmaf(a, bflo(w.w), o1.z); o1.w = fmaf(a, bfhi(w.w), o1.w);
  }
  float4* op = out4 + ((size_t)bb * N + n) * 16 + og * 2;
  float4 c0 = op[0], c1 = op[1];
  c0.x += o0.x; c0.y += o0.y; c0.z += o0.z; c0.w += o0.w;
  c1.x += o1.x; c1.y += o1.y; c1.z += o1.z; c1.w += o1.w;
  op[0] = c0;
  op[1] = c1;
}

// ---------------- launch ----------------

extern "C" void kernel_launch(void* const* d_in, const int* in_sizes, int n_in,
                              void* d_out, int out_size, void* d_ws, size_t ws_size,
                              hipStream_t stream) {
  const float* inp = (const float*)d_in[0];
  const int*   rws[2] = {(const int*)d_in[1], (const int*)d_in[4]};
  const int*   cls[2] = {(const int*)d_in[2], (const int*)d_in[5]};
  const float* vls[2] = {(const float*)d_in[3], (const float*)d_in[6]};
  const float* W    = (const float*)d_in[7];
  const float* bias = (const float*)d_in[8];
  float* out = (float*)d_out;

  const int N = in_sizes[0] / C;          // 20000
  const int Emax = (in_sizes[1] > in_sizes[4]) ? in_sizes[1] : in_sizes[4];

  // workspace layout
  char* ws = (char*)d_ws;
  size_t rowBytes = (size_t)C * 2;                       // 4096 B per node (bf16)
  ushort* x0b = (ushort*)ws;               size_t off = (size_t)N * rowBytes;  // 81.92 MB
  ushort* X1b = (ushort*)(ws + off);       off += (size_t)N * rowBytes;        // 81.92 MB
  int2*  edges = (int2*)(ws + off);        off += (size_t)Emax * 8;            // 5.12 MB
  int*   row_ptr = (int*)(ws + off);       off += (size_t)(N + 1) * 4;
  off = (off + 255) & ~(size_t)255;
  int*   counts = (int*)(ws + off);        off += (size_t)N * 4;
  (void)ws_size; (void)n_in; (void)out_size;             // needs ~170 MB of ws

  pack_x0<<<(N * 512 + 255) / 256, 256, 0, stream>>>((const float4*)inp,
                                                     (ushort4*)x0b, N);

  dim3 g0((N + 63) / 64, B);
  k0_gemm<<<g0, 256, 0, stream>>>((const float4*)inp, (const float4*)W,
                                  (const float4*)bias, (float4*)out, N);

  for (int s = 0; s < 2; ++s) {
    const int E = in_sizes[s == 0 ? 1 : 4];
    const int* rows = rws[s];
    const int* cols = cls[s];
    const float* vals = vls[s];

    hipMemsetAsync(counts, 0, (size_t)N * 4, stream);
    hist_k<<<(E + 255) / 256, 256, 0, stream>>>(rows, counts, E);
    scan_k<<<1, 256, 0, stream>>>(counts, row_ptr, N);
    hipMemsetAsync(counts, 0, (size_t)N * 4, stream);
    fill_k<<<(E + 255) / 256, 256, 0, stream>>>(rows, cols, vals, row_ptr, counts,
                                                edges, E);

    const float4* W1 = (const float4*)(W + (size_t)(s * 3 + 1) * 64 * 64);
    const float4* W2 = (const float4*)(W + (size_t)(s * 3 + 2) * 64 * 64);

    // hop 1: X1 = A*x0 (bf16 gather), project with W1
    spmm_proj<true><<<N, 256, 0, stream>>>((const uint4*)x0b, row_ptr, edges, W1,
                                           (uint4*)X1b, (float4*)out, N);
    // hop 2: A*X1, project with W2 (X2 never materialized)
    spmm_proj<false><<<N, 256, 0, stream>>>((const uint4*)X1b, row_ptr, edges, W2,
                                            nullptr, (float4*)out, N);
  }
}

// Round 3
// 3429.890 us; speedup vs baseline: 2.7284x; 2.7284x over previous
//
#include <hip/hip_runtime.h>

// DiffusionConvolution: out[b,n,o] = bias[o] + sum_{s,k,d} (A_s^k x0)[n,(d,b)] * W[(3s+k)*64+d, o]
// B=32, N=20000, D=OUT=64, K=2, E=640000 per support.
//
// R3 structure: per support s:
//   CSR build (ecol/eval, separate arrays, uniform SMEM loads in spmm)
//   spmm1: X1 = A*x0   — fp32 gather from inp (R1-proven pattern), write X1 bf16 (82 MB)
//   spmm2: X2 = A*X1   — bf16 gather (uint4/thread), write X2 bf16
//   proj_gemm<ADD=s>:  out (+)= inp*Wk0_s + X1*W_{s,1} + X2*W_{s,2} (+bias on s=0)
// No out-RMW inside the SpMMs (R2's 5.6 GB write pathology lived there).
// Workspace: X1 82 + X2 82 + edges 5.1 + ptr/counts ~0.2 = ~170 MB (R1-proven size).

constexpr int B = 32;
constexpr int D = 64;
constexpr int C = B * D;   // 2048 features per node

__device__ __forceinline__ void fma4(float4& a, float s, const float4 b) {
  a.x = fmaf(s, b.x, a.x);
  a.y = fmaf(s, b.y, a.y);
  a.z = fmaf(s, b.z, a.z);
  a.w = fmaf(s, b.w, a.w);
}

__device__ __forceinline__ unsigned f2bf(float f) {
  union { float f; unsigned u; } v; v.f = f;
  return (v.u + 0x7fffu + ((v.u >> 16) & 1u)) >> 16;   // RNE
}
__device__ __forceinline__ unsigned pk(float a, float b) {
  return f2bf(a) | (f2bf(b) << 16);
}
__device__ __forceinline__ float bflo(unsigned u) { return __uint_as_float(u << 16); }
__device__ __forceinline__ float bfhi(unsigned u) { return __uint_as_float(u & 0xffff0000u); }

__device__ __forceinline__ void fma8(float4& a0, float4& a1, float v, uint4 u) {
  a0.x = fmaf(v, bflo(u.x), a0.x); a0.y = fmaf(v, bfhi(u.x), a0.y);
  a0.z = fmaf(v, bflo(u.y), a0.z); a0.w = fmaf(v, bfhi(u.y), a0.w);
  a1.x = fmaf(v, bflo(u.z), a1.x); a1.y = fmaf(v, bfhi(u.z), a1.y);
  a1.z = fmaf(v, bflo(u.w), a1.z); a1.w = fmaf(v, bfhi(u.w), a1.w);
}

// ---------------- CSR build ----------------

__global__ __launch_bounds__(256) void hist_k(const int* __restrict__ rows,
                                              int* __restrict__ counts, int E) {
  int e = blockIdx.x * 256 + threadIdx.x;
  if (e < E) atomicAdd(&counts[rows[e]], 1);
}

__global__ __launch_bounds__(256) void scan_k(const int* __restrict__ counts,
                                              int* __restrict__ row_ptr, int N) {
  __shared__ int part[256];
  int t = threadIdx.x;
  int chunk = (N + 255) >> 8;
  int lo = t * chunk; if (lo > N) lo = N;
  int hi = lo + chunk; if (hi > N) hi = N;
  int s = 0;
  for (int i = lo; i < hi; ++i) s += counts[i];
  part[t] = s;
  __syncthreads();
  for (int off = 1; off < 256; off <<= 1) {
    int x = (t >= off) ? part[t - off] : 0;
    __syncthreads();
    part[t] += x;
    __syncthreads();
  }
  int run = part[t] - s;
  for (int i = lo; i < hi; ++i) { row_ptr[i] = run; run += counts[i]; }
  if (t == 255) row_ptr[N] = part[255];
}

__global__ __launch_bounds__(256) void fill_k(const int* __restrict__ rows,
                                              const int* __restrict__ cols,
                                              const float* __restrict__ vals,
                                              const int* __restrict__ row_ptr,
                                              int* __restrict__ cursor,
                                              int* __restrict__ ecol,
                                              float* __restrict__ eval, int E) {
  int e = blockIdx.x * 256 + threadIdx.x;
  if (e < E) {
    int r = rows[e];
    int pos = row_ptr[r] + atomicAdd(&cursor[r], 1);
    ecol[pos] = cols[e];
    eval[pos] = vals[e];
  }
}

// ---------------- spmm1: X1 = A * x0, fp32 gather from inp, bf16 write ----------------
// One block per row n. Thread t: b0=t>>4 (acc0), b0+16 (acc1), float4 d-chunk t&15.

__global__ __launch_bounds__(256) void spmm1(const float4* __restrict__ inp4,
                                             const int* __restrict__ row_ptr,
                                             const int* __restrict__ ecol,
                                             const float* __restrict__ eval,
                                             uint2* __restrict__ X1u2, int N) {
  int t = threadIdx.x;
  int n = blockIdx.x;
  float4 acc0 = {0.f, 0.f, 0.f, 0.f};
  float4 acc1 = {0.f, 0.f, 0.f, 0.f};
  int start = row_ptr[n], end = row_ptr[n + 1];
  const float4* p0 = inp4 + (size_t)(t >> 4) * (N * 16) + (t & 15);
  const float4* p1 = inp4 + (size_t)((t >> 4) + 16) * (N * 16) + (t & 15);
  for (int e = start; e < end; ++e) {
    int col = ecol[e];
    float v = eval[e];
    fma4(acc0, v, p0[(size_t)col * 16]);
    fma4(acc1, v, p1[(size_t)col * 16]);
  }
  // X1 row layout [b*64+d]; thread feats: b=(t>>4), d=(t&15)*4 .. +3 (and b+16)
  size_t idx = (size_t)n * 512 + (t >> 4) * 16 + (t & 15);
  X1u2[idx]       = make_uint2(pk(acc0.x, acc0.y), pk(acc0.z, acc0.w));
  X1u2[idx + 256] = make_uint2(pk(acc1.x, acc1.y), pk(acc1.z, acc1.w));
}

// ---------------- spmm2: X2 = A * X1, bf16 gather, bf16 write ----------------
// One block per row n. Thread t owns feats 8t..8t+7 (one uint4 per edge).

__global__ __launch_bounds__(256) void spmm2(const uint4* __restrict__ X1u4,
                                             const int* __restrict__ row_ptr,
                                             const int* __restrict__ ecol,
                                             const float* __restrict__ eval,
                                             uint4* __restrict__ X2u4, int N) {
  int t = threadIdx.x;
  int n = blockIdx.x;
  float4 acc0 = {0.f, 0.f, 0.f, 0.f};
  float4 acc1 = {0.f, 0.f, 0.f, 0.f};
  int start = row_ptr[n], end = row_ptr[n + 1];
  const uint4* sp = X1u4 + t;
  int e = start;
  for (; e + 2 <= end; e += 2) {
    int c0 = ecol[e], c1 = ecol[e + 1];
    float v0 = eval[e], v1 = eval[e + 1];
    uint4 u0 = sp[(size_t)c0 * 256];
    uint4 u1 = sp[(size_t)c1 * 256];
    fma8(acc0, acc1, v0, u0);
    fma8(acc0, acc1, v1, u1);
  }
  if (e < end) {
    uint4 u0 = sp[(size_t)ecol[e] * 256];
    fma8(acc0, acc1, eval[e], u0);
  }
  X2u4[(size_t)n * 256 + t] = make_uint4(pk(acc0.x, acc0.y), pk(acc0.z, acc0.w),
                                         pk(acc1.x, acc1.y), pk(acc1.z, acc1.w));
}

// ---------------- proj_gemm: out (+)= inp*Wk0 + X1*W1 + X2*W2 (+bias) ----------------
// grid ((N+63)/64, B), block 256. Tile 64n x 64o, thread tile 2n x 8o.
// Sources looped through one sA buffer; W slices via sW. LDS 16.6+16 = 32.6 KB.

template <bool ADD>
__global__ __launch_bounds__(256) void proj_gemm(const float4* __restrict__ inp4,
                                                 const uint2* __restrict__ X1u2,
                                                 const uint2* __restrict__ X2u2,
                                                 const float4* __restrict__ W4,
                                                 int w_row0,   // 192*s: W rows (w_row0 + j*64 + d)
                                                 const float4* __restrict__ bias4,
                                                 float4* __restrict__ out4, int N) {
  __shared__ float sA[64 * 65];
  __shared__ float4 sW[64 * 16];
  int t = threadIdx.x;
  int b = blockIdx.y;
  int n0 = blockIdx.x * 64;

  int np = t >> 3;                  // row pair np*2, np*2+1
  int og = t & 7;                   // outs og*8..+7
  float4 a00, a01, a10, a11;
  if (ADD) {
    a00 = a01 = a10 = a11 = make_float4(0.f, 0.f, 0.f, 0.f);
  } else {
    float4 bz0 = bias4[og * 2], bz1 = bias4[og * 2 + 1];
    a00 = bz0; a01 = bz1; a10 = bz0; a11 = bz1;
  }

  for (int j = 0; j < 3; ++j) {
    // stage W slice j: rows w_row0 + j*64 + d
#pragma unroll
    for (int k = 0; k < 4; ++k) {
      int l = t + 256 * k;          // d = l>>4, o4 = l&15
      sW[l] = W4[(size_t)(w_row0 + j * 64) * 16 + l];
    }
    // stage A tile: 64 rows x 64 d (this b)
    if (j == 0) {
#pragma unroll
      for (int k = 0; k < 4; ++k) {
        int q = t + 256 * k;
        int r = q >> 4, d4 = q & 15;
        int n = n0 + r;
        float4 v = {0.f, 0.f, 0.f, 0.f};
        if (n < N) v = inp4[((size_t)b * N + n) * 16 + d4];
        float* sp = &sA[r * 65 + d4 * 4];
        sp[0] = v.x; sp[1] = v.y; sp[2] = v.z; sp[3] = v.w;
      }
    } else {
      const uint2* Xs = (j == 1) ? X1u2 : X2u2;
#pragma unroll
      for (int k = 0; k < 4; ++k) {
        int q = t + 256 * k;
        int r = q >> 4, jj = q & 15;  // feats jj*4..+3 of (b,row)
        int n = n0 + r;
        uint2 u = make_uint2(0u, 0u);
        if (n < N) u = Xs[(size_t)n * 512 + b * 16 + jj];
        float* sp = &sA[r * 65 + jj * 4];
        sp[0] = bflo(u.x); sp[1] = bfhi(u.x);
        sp[2] = bflo(u.y); sp[3] = bfhi(u.y);
      }
    }
    __syncthreads();

    const float* ap0 = &sA[(np * 2) * 65];
    const float* ap1 = ap0 + 65;
#pragma unroll
    for (int d = 0; d < 64; ++d) {
      float x0 = ap0[d], x1 = ap1[d];
      float4 w0 = sW[d * 16 + og * 2];
      float4 w1 = sW[d * 16 + og * 2 + 1];
      fma4(a00, x0, w0); fma4(a01, x0, w1);
      fma4(a10, x1, w0); fma4(a11, x1, w1);
    }
    __syncthreads();
  }

  int n = n0 + np * 2;
  if (n < N) {
    float4* op = &out4[((size_t)b * N + n) * 16 + og * 2];
    if (ADD) {
      float4 c0 = op[0], c1 = op[1];
      c0.x += a00.x; c0.y += a00.y; c0.z += a00.z; c0.w += a00.w;
      c1.x += a01.x; c1.y += a01.y; c1.z += a01.z; c1.w += a01.w;
      op[0] = c0; op[1] = c1;
    } else {
      op[0] = a00; op[1] = a01;
    }
  }
  if (n + 1 < N) {
    float4* op = &out4[((size_t)b * N + n + 1) * 16 + og * 2];
    if (ADD) {
      float4 c0 = op[0], c1 = op[1];
      c0.x += a10.x; c0.y += a10.y; c0.z += a10.z; c0.w += a10.w;
      c1.x += a11.x; c1.y += a11.y; c1.z += a11.z; c1.w += a11.w;
      op[0] = c0; op[1] = c1;
    } else {
      op[0] = a10; op[1] = a11;
    }
  }
}

// ---------------- launch ----------------

extern "C" void kernel_launch(void* const* d_in, const int* in_sizes, int n_in,
                              void* d_out, int out_size, void* d_ws, size_t ws_size,
                              hipStream_t stream) {
  const float* inp = (const float*)d_in[0];
  const int*   rws[2] = {(const int*)d_in[1], (const int*)d_in[4]};
  const int*   cls[2] = {(const int*)d_in[2], (const int*)d_in[5]};
  const float* vls[2] = {(const float*)d_in[3], (const float*)d_in[6]};
  const float* W    = (const float*)d_in[7];
  const float* bias = (const float*)d_in[8];
  float* out = (float*)d_out;

  const int N = in_sizes[0] / C;          // 20000
  const int Emax = (in_sizes[1] > in_sizes[4]) ? in_sizes[1] : in_sizes[4];

  // workspace layout (~170 MB)
  char* ws = (char*)d_ws;
  size_t rowBytes = (size_t)C * 2;                        // 4096 B/node bf16
  ushort* X1 = (ushort*)ws;                size_t off = (size_t)N * rowBytes;  // 81.92 MB
  ushort* X2 = (ushort*)(ws + off);        off += (size_t)N * rowBytes;        // 81.92 MB
  int*   ecol = (int*)(ws + off);          off += (size_t)Emax * 4;
  float* evalv = (float*)(ws + off);       off += (size_t)Emax * 4;
  int*   row_ptr = (int*)(ws + off);       off += (size_t)(N + 1) * 4;
  off = (off + 255) & ~(size_t)255;
  int*   counts = (int*)(ws + off);        off += (size_t)N * 4;
  (void)ws_size; (void)n_in; (void)out_size;

  dim3 gp((N + 63) / 64, B);

  for (int s = 0; s < 2; ++s) {
    const int E = in_sizes[s == 0 ? 1 : 4];

    hipMemsetAsync(counts, 0, (size_t)N * 4, stream);
    hist_k<<<(E + 255) / 256, 256, 0, stream>>>(rws[s], counts, E);
    scan_k<<<1, 256, 0, stream>>>(counts, row_ptr, N);
    hipMemsetAsync(counts, 0, (size_t)N * 4, stream);
    fill_k<<<(E + 255) / 256, 256, 0, stream>>>(rws[s], cls[s], vls[s], row_ptr,
                                                counts, ecol, evalv, E);

    spmm1<<<N, 256, 0, stream>>>((const float4*)inp, row_ptr, ecol, evalv,
                                 (uint2*)X1, N);
    spmm2<<<N, 256, 0, stream>>>((const uint4*)X1, row_ptr, ecol, evalv,
                                 (uint4*)X2, N);

    if (s == 0) {
      proj_gemm<false><<<gp, 256, 0, stream>>>((const float4*)inp, (const uint2*)X1,
                                               (const uint2*)X2, (const float4*)W, 0,
                                               (const float4*)bias, (float4*)out, N);
    } else {
      proj_gemm<true><<<gp, 256, 0, stream>>>((const float4*)inp, (const uint2*)X1,
                                              (const uint2*)X2, (const float4*)W, 192,
                                              (const float4*)bias, (float4*)out, N);
    }
  }
}